// Round 5
// baseline (1336.261 us; speedup 1.0000x reference)
//
#include <hip/hip_runtime.h>
#include <hip/hip_bf16.h>

#define NN 100000
#define EE 1600000
#define GG 512
#define NB ((NN + 255) / 256)   // 391 blocks for node-sized scans

// ---- in-degree histogram (int) ----
__global__ void deg_kernel(const int* __restrict__ ei, int* __restrict__ cnt, int E_) {
    int e = blockIdx.x * 256 + threadIdx.x;
    if (e < E_) atomicAdd(&cnt[ei[E_ + e]], 1);
}

// ---- block sums for scan ----
__global__ void blocksum(const int* __restrict__ cnt, int* __restrict__ bsum) {
    __shared__ int sh[256];
    int i = blockIdx.x * 256 + threadIdx.x;
    sh[threadIdx.x] = (i < NN) ? cnt[i] : 0;
    __syncthreads();
    for (int o = 128; o > 0; o >>= 1) {
        if (threadIdx.x < o) sh[threadIdx.x] += sh[threadIdx.x + o];
        __syncthreads();
    }
    if (threadIdx.x == 0) bsum[blockIdx.x] = sh[0];
}

// ---- exclusive scan of block sums (1 block, 512 threads, nb<=512) ----
__global__ void scan_bsum(int* __restrict__ bsum, int nb) {
    __shared__ int sh[512];
    int t = threadIdx.x;
    int v = (t < nb) ? bsum[t] : 0;
    int orig = v;
    sh[t] = v;
    __syncthreads();
    for (int o = 1; o < 512; o <<= 1) {
        int add = (t >= o) ? sh[t - o] : 0;
        __syncthreads();
        sh[t] += add;
        __syncthreads();
    }
    if (t < nb) bsum[t] = sh[t] - orig;   // exclusive
}

// ---- final scan: row_ptr + cursor + dinv ----
__global__ void scan_final(const int* __restrict__ cnt, const int* __restrict__ boff,
                           int* __restrict__ row_ptr, int* __restrict__ cursor,
                           float* __restrict__ dinv) {
    __shared__ int sh[256];
    int i = blockIdx.x * 256 + threadIdx.x;
    int v = (i < NN) ? cnt[i] : 0;
    int orig = v;
    sh[threadIdx.x] = v;
    __syncthreads();
    for (int o = 1; o < 256; o <<= 1) {
        int add = (threadIdx.x >= o) ? sh[threadIdx.x - o] : 0;
        __syncthreads();
        sh[threadIdx.x] += add;
        __syncthreads();
    }
    if (i < NN) {
        int ex = boff[blockIdx.x] + sh[threadIdx.x] - orig;
        row_ptr[i] = ex;
        cursor[i] = ex;
        dinv[i] = rsqrtf((float)orig + 1.0f);
    }
    if (i == 0) row_ptr[NN] = EE;
}

// ---- fill CSR: packed (src-as-float, norm) per edge, bucketed by dst ----
__global__ void fill_csr(const int* __restrict__ ei, const float* __restrict__ dinv,
                         int* __restrict__ cursor, float2* __restrict__ ent, int E_) {
    int e = blockIdx.x * 256 + threadIdx.x;
    if (e < E_) {
        int s = ei[e], d = ei[E_ + e];
        int pos = atomicAdd(&cursor[d], 1);
        float2 v;
        v.x = __int_as_float(s);
        v.y = dinv[s] * dinv[d];
        ent[pos] = v;
    }
}

// ---- column stats: stats[0:64]=sum, stats[64:128]=sumsq ----
__global__ void colstats(const float* __restrict__ A, int nrows, float* __restrict__ stats) {
    __shared__ float ssum[4][64];
    __shared__ float ssq[4][64];
    int tid = threadIdx.x;
    int col = tid & 63, rg = tid >> 6;
    float s = 0.f, q = 0.f;
    for (int r = blockIdx.x * 4 + rg; r < nrows; r += gridDim.x * 4) {
        float v = A[r * 64 + col];
        s += v;
        q = fmaf(v, v, q);
    }
    ssum[rg][col] = s; ssq[rg][col] = q;
    __syncthreads();
    if (tid < 64) {
        float ts = ssum[0][tid] + ssum[1][tid] + ssum[2][tid] + ssum[3][tid];
        float tq = ssq[0][tid] + ssq[1][tid] + ssq[2][tid] + ssq[3][tid];
        atomicAdd(&stats[tid], ts);
        atomicAdd(&stats[64 + tid], tq);
    }
}

// ---- fold BN into weights ----
__global__ void prep(const float* __restrict__ stats, float count,
                     const float* __restrict__ g, const float* __restrict__ b,
                     const float* __restrict__ W, const float* __restrict__ basebias,
                     float* __restrict__ Wp, float* __restrict__ bp) {
    int j = threadIdx.x;  // 64 threads
    float acc = basebias ? basebias[j] : 0.f;
    for (int k = 0; k < 64; k++) {
        float mu  = stats[k] / count;
        float var = fmaxf(stats[64 + k] / count - mu * mu, 0.f);
        float rstd = rsqrtf(var + 1e-5f);
        float a = rstd * g[k];
        float w = W[k * 64 + j];
        Wp[k * 64 + j] = a * w;
        acc = fmaf(b[k] - mu * a, w, acc);
    }
    bp[j] = acc;
}

// ---- C = (relu?)(A@Wp + bp); fp32 out (C) and/or bf16 out (Cb); optional fused stats ----
__global__ __launch_bounds__(256) void gemm64(const float* __restrict__ A,
                                              const float* __restrict__ Wp,
                                              const float* __restrict__ bp,
                                              float* __restrict__ C,
                                              __hip_bfloat16* __restrict__ Cb,
                                              int nrows, int dorelu,
                                              float* __restrict__ stats) {
    __shared__ float Ws[64 * 64];
    __shared__ float As[64 * 64];
    __shared__ float ssh[256];
    __shared__ float qsh[256];
    int tid = threadIdx.x;
    int row0 = blockIdx.x * 64;
    const float4* A4 = (const float4*)(A + (size_t)row0 * 64);
    const float4* W4 = (const float4*)Wp;
    for (int i = tid; i < 1024; i += 256) {
        ((float4*)Ws)[i] = W4[i];
        int r = row0 + (i >> 4);
        float4 v;
        if (r < nrows) v = A4[i];
        else { v.x = v.y = v.z = v.w = 0.f; }
        ((float4*)As)[i] = v;
    }
    __syncthreads();
    int col = tid & 63;
    int rg = tid >> 6;  // 0..3
    float bcol = bp[col];
    float s = 0.f, q = 0.f;
    for (int rr = rg; rr < 64; rr += 4) {
        int r = row0 + rr;
        if (r >= nrows) break;
        float acc = bcol;
#pragma unroll
        for (int k = 0; k < 64; k++) acc = fmaf(As[rr * 64 + k], Ws[k * 64 + col], acc);
        float v = dorelu ? fmaxf(acc, 0.f) : acc;
        if (C)  C[(size_t)r * 64 + col] = v;
        if (Cb) Cb[(size_t)r * 64 + col] = __float2bfloat16(v);
        s += v;
        q = fmaf(v, v, q);
    }
    if (stats) {
        ssh[tid] = s; qsh[tid] = q;
        __syncthreads();
        if (tid < 64) {
            float ts = ssh[tid] + ssh[64 + tid] + ssh[128 + tid] + ssh[192 + tid];
            float tq = qsh[tid] + qsh[64 + tid] + qsh[128 + tid] + qsh[192 + tid];
            atomicAdd(&stats[tid], ts);
            atomicAdd(&stats[64 + tid], tq);
        }
    }
}

// unpack uint2 (4 bf16) -> 4 floats, FMA into a0..a3
#define FMA4(W, Q)                                                              \
    { float f0 = __uint_as_float((Q).x << 16);                                  \
      float f1 = __uint_as_float((Q).x & 0xffff0000u);                          \
      float f2 = __uint_as_float((Q).y << 16);                                  \
      float f3 = __uint_as_float((Q).y & 0xffff0000u);                          \
      a0 = fmaf((W), f0, a0); a1 = fmaf((W), f1, a1);                           \
      a2 = fmaf((W), f2, a2); a3 = fmaf((W), f3, a3); }

// ---- fused CSR gather over bf16 m rows (128 B each), 16 lanes/node x 4 cols ----
// hn = h + relu(dinv^2*m[i] + sum_e norm*m[src] + cb); optional writeH / stats / pool.
// Grid MUST be exactly NN/16 blocks.
__global__ __launch_bounds__(256) void gather(const int* __restrict__ row_ptr,
                                              const float2* __restrict__ ent,
                                              const float* __restrict__ dinv,
                                              const uint2* __restrict__ mq2,
                                              float* __restrict__ h,
                                              const float* __restrict__ cb,
                                              float* __restrict__ stats,
                                              float* __restrict__ pooled,
                                              const int* __restrict__ batch,
                                              int writeH) {
    int tid = threadIdx.x;
    int ng = tid >> 4;        // 16 nodes per block
    int li = tid & 15;        // 16 lanes/node; lane covers cols li*4..li*4+3
    int i = blockIdx.x * 16 + ng;

    float a0, a1, a2, a3;
    {
        float di = dinv[i];
        float d2 = di * di;
        uint2 qs = mq2[(size_t)i * 16 + li];
        float f0 = __uint_as_float(qs.x << 16);
        float f1 = __uint_as_float(qs.x & 0xffff0000u);
        float f2 = __uint_as_float(qs.y << 16);
        float f3 = __uint_as_float(qs.y & 0xffff0000u);
        a0 = d2 * f0; a1 = d2 * f1; a2 = d2 * f2; a3 = d2 * f3;
    }
    int e = row_ptr[i], e1 = row_ptr[i + 1];

    // 8-wide: up to 8 independent row-gathers in flight
    for (; e + 8 <= e1; e += 8) {
        float2 c0 = ent[e + 0], c1 = ent[e + 1], c2 = ent[e + 2], c3 = ent[e + 3];
        float2 c4 = ent[e + 4], c5 = ent[e + 5], c6 = ent[e + 6], c7 = ent[e + 7];
        uint2 r0 = mq2[(size_t)__float_as_int(c0.x) * 16 + li];
        uint2 r1 = mq2[(size_t)__float_as_int(c1.x) * 16 + li];
        uint2 r2 = mq2[(size_t)__float_as_int(c2.x) * 16 + li];
        uint2 r3 = mq2[(size_t)__float_as_int(c3.x) * 16 + li];
        uint2 r4 = mq2[(size_t)__float_as_int(c4.x) * 16 + li];
        uint2 r5 = mq2[(size_t)__float_as_int(c5.x) * 16 + li];
        uint2 r6 = mq2[(size_t)__float_as_int(c6.x) * 16 + li];
        uint2 r7 = mq2[(size_t)__float_as_int(c7.x) * 16 + li];
        FMA4(c0.y, r0); FMA4(c1.y, r1); FMA4(c2.y, r2); FMA4(c3.y, r3);
        FMA4(c4.y, r4); FMA4(c5.y, r5); FMA4(c6.y, r6); FMA4(c7.y, r7);
    }
    if (e + 4 <= e1) {
        float2 c0 = ent[e + 0], c1 = ent[e + 1], c2 = ent[e + 2], c3 = ent[e + 3];
        uint2 r0 = mq2[(size_t)__float_as_int(c0.x) * 16 + li];
        uint2 r1 = mq2[(size_t)__float_as_int(c1.x) * 16 + li];
        uint2 r2 = mq2[(size_t)__float_as_int(c2.x) * 16 + li];
        uint2 r3 = mq2[(size_t)__float_as_int(c3.x) * 16 + li];
        FMA4(c0.y, r0); FMA4(c1.y, r1); FMA4(c2.y, r2); FMA4(c3.y, r3);
        e += 4;
    }
    for (; e < e1; e++) {
        float2 c = ent[e];
        uint2 r = mq2[(size_t)__float_as_int(c.x) * 16 + li];
        FMA4(c.y, r);
    }

    float4 hb = ((const float4*)h)[(size_t)i * 16 + li];
    float4 cbv = ((const float4*)cb)[li];
    float n0 = hb.x + fmaxf(a0 + cbv.x, 0.f);
    float n1 = hb.y + fmaxf(a1 + cbv.y, 0.f);
    float n2 = hb.z + fmaxf(a2 + cbv.z, 0.f);
    float n3 = hb.w + fmaxf(a3 + cbv.w, 0.f);
    if (writeH) {
        float4 o; o.x = n0; o.y = n1; o.z = n2; o.w = n3;
        ((float4*)h)[(size_t)i * 16 + li] = o;
    }
    if (pooled) {
        int g = batch[i];
        float* p = pooled + g * 64 + li * 4;
        atomicAdd(p + 0, n0); atomicAdd(p + 1, n1);
        atomicAdd(p + 2, n2); atomicAdd(p + 3, n3);
    }
    if (stats) {
        __shared__ float rs[256 * 4];
        __shared__ float rq[256 * 4];
        rs[tid * 4 + 0] = n0; rs[tid * 4 + 1] = n1; rs[tid * 4 + 2] = n2; rs[tid * 4 + 3] = n3;
        rq[tid * 4 + 0] = n0 * n0; rq[tid * 4 + 1] = n1 * n1;
        rq[tid * 4 + 2] = n2 * n2; rq[tid * 4 + 3] = n3 * n3;
        __syncthreads();
        if (tid < 64) {  // tid = cl2*4+k -> column cl2*4+k == tid
            int cl2 = tid >> 2, k = tid & 3;
            float a = 0.f, b = 0.f;
            for (int g2 = 0; g2 < 16; g2++) {
                a += rs[(g2 * 16 + cl2) * 4 + k];
                b += rq[(g2 * 16 + cl2) * 4 + k];
            }
            atomicAdd(&stats[tid], a);
            atomicAdd(&stats[64 + tid], b);
        }
    }
}

// ---- final BN apply ----
__global__ void bn_apply(const float* __restrict__ A, const float* __restrict__ stats, float count,
                         const float* __restrict__ g, const float* __restrict__ b,
                         float* __restrict__ out, int total) {
    int idx = blockIdx.x * 256 + threadIdx.x;
    if (idx < total) {
        int j = idx & 63;
        float mu  = stats[j] / count;
        float var = fmaxf(stats[64 + j] / count - mu * mu, 0.f);
        float rstd = rsqrtf(var + 1e-5f);
        out[idx] = (A[idx] - mu) * rstd * g[j] + b[j];
    }
}

extern "C" void kernel_launch(void* const* d_in, const int* in_sizes, int n_in,
                              void* d_out, int out_size, void* d_ws, size_t ws_size,
                              hipStream_t stream) {
    const float* x     = (const float*)d_in[0];
    const int*   ei    = (const int*)d_in[1];
    const int*   batch = (const int*)d_in[2];
    const float* bnfg  = (const float*)d_in[3];
    const float* bnfb  = (const float*)d_in[4];
    const float* linW  = (const float*)d_in[5];
    const float* linb  = (const float*)d_in[6];
    const float* bncg  = (const float*)d_in[7];
    const float* bncb  = (const float*)d_in[8];
    const float* convW = (const float*)d_in[9];
    const float* convb = (const float*)d_in[10];
    const float* bnfcg = (const float*)d_in[11];
    const float* bnfcb = (const float*)d_in[12];
    const float* fcW   = (const float*)d_in[13];
    const float* fcb   = (const float*)d_in[14];
    const float* bnhg  = (const float*)d_in[15];
    const float* bnhb  = (const float*)d_in[16];

    const int N64 = NN * 64;
    float* ws = (float*)d_ws;
    size_t o = 0;
    int*    cnt     = (int*)(ws + o);    o += 100352;
    float*  dinv    = ws + o;            o += 100352;
    int*    row_ptr = (int*)(ws + o);    o += 100352;
    int*    cursor  = (int*)(ws + o);    o += 100352;
    int*    bsum    = (int*)(ws + o);    o += 512;
    float2* ent     = (float2*)(ws + o); o += 2 * (size_t)EE;
    float*  h       = ws + o;            o += N64;
    __hip_bfloat16* mb = (__hip_bfloat16*)(ws + o); o += N64 / 2;  // bf16 m
    float*  statsA  = ws + o;            o += 128;
    float*  statsB  = ws + o;            o += 128;
    float*  Wp      = ws + o;            o += 4096;
    float*  bp      = ws + o;            o += 64;
    float*  pa      = ws + o;            o += GG * 64;
    float*  pb      = ws + o;            o += GG * 64;

    // --- CSR build ---
    hipMemsetAsync(cnt, 0, NN * sizeof(int), stream);
    deg_kernel<<<(EE + 255) / 256, 256, 0, stream>>>(ei, cnt, EE);
    blocksum<<<NB, 256, 0, stream>>>(cnt, bsum);
    scan_bsum<<<1, 512, 0, stream>>>(bsum, NB);
    scan_final<<<NB, 256, 0, stream>>>(cnt, bsum, row_ptr, cursor, dinv);
    fill_csr<<<(EE + 255) / 256, 256, 0, stream>>>(ei, dinv, cursor, ent, EE);

    // --- stem: h = relu(BN(x)@linW + linb), fused stats(h) -> statsB ---
    hipMemsetAsync(statsA, 0, 512, stream);
    colstats<<<256, 256, 0, stream>>>(x, NN, statsA);
    prep<<<1, 64, 0, stream>>>(statsA, (float)NN, bnfg, bnfb, linW, linb, Wp, bp);
    hipMemsetAsync(statsB, 0, 512, stream);
    gemm64<<<(NN + 63) / 64, 256, 0, stream>>>(x, Wp, bp, h, nullptr, NN, 1, statsB);

    // --- conv layers ---
    hipMemsetAsync(pa, 0, GG * 64 * sizeof(float), stream);
    float* cur = statsB; float* nxt = statsA;
    for (int l = 0; l < 4; l++) {
        prep<<<1, 64, 0, stream>>>(cur, (float)NN, bncg + 64 * l, bncb + 64 * l,
                                   convW + 4096 * l, nullptr, Wp, bp);
        gemm64<<<(NN + 63) / 64, 256, 0, stream>>>(h, Wp, bp, nullptr, mb, NN, 0, nullptr);
        if (l < 3) {
            hipMemsetAsync(nxt, 0, 512, stream);
            gather<<<NN / 16, 256, 0, stream>>>(row_ptr, ent, dinv, (const uint2*)mb, h,
                                                convb + 64 * l, nxt, nullptr, batch, 1);
        } else {
            gather<<<NN / 16, 256, 0, stream>>>(row_ptr, ent, dinv, (const uint2*)mb, h,
                                                convb + 64 * l, nullptr, pa, batch, 0);
        }
        float* t = cur; cur = nxt; nxt = t;
    }

    // --- fc head ---
    float* pin = pa; float* pout = pb;
    for (int i = 0; i < 2; i++) {
        hipMemsetAsync(statsA, 0, 512, stream);
        colstats<<<8, 256, 0, stream>>>(pin, GG, statsA);
        prep<<<1, 64, 0, stream>>>(statsA, (float)GG, bnfcg + 64 * i, bnfcb + 64 * i,
                                   fcW + 4096 * i, fcb + 64 * i, Wp, bp);
        gemm64<<<(GG + 63) / 64, 256, 0, stream>>>(pin, Wp, bp, pout, nullptr, GG, 1, nullptr);
        float* t = pin; pin = pout; pout = t;
    }

    // --- final BN -> d_out ---
    hipMemsetAsync(statsA, 0, 512, stream);
    colstats<<<8, 256, 0, stream>>>(pin, GG, statsA);
    bn_apply<<<(GG * 64 + 255) / 256, 256, 0, stream>>>(pin, statsA, (float)GG, bnhg, bnhb,
                                                        (float*)d_out, GG * 64);
}